// Round 3
// baseline (1228.929 us; speedup 1.0000x reference)
//
#include <hip/hip_runtime.h>
#include <math.h>

typedef __attribute__((ext_vector_type(8))) short bf16x8;
typedef __attribute__((ext_vector_type(4))) float f32x4;

#define NBLK 1024
#define TPB 256
#define WFRAG (16 * 4 * 64 * 8)

// ---------------- helpers ----------------

__device__ inline int detect_is64(const int* __restrict__ ei) {
    int is64 = 1;
#pragma unroll
    for (int k = 1; k < 16; k += 2) is64 &= (ei[k] == 0);
    return is64;
}

__device__ inline void split1(float f, short& hi, short& lo) {
    unsigned u = __float_as_uint(f);
    hi = (short)(u >> 16);
    float fl = f - __uint_as_float(u & 0xffff0000u);
    lo = (short)(__float_as_uint(fl) >> 16);
}

__device__ inline void cvt8(const float4& a, const float4& b, bf16x8& hi, bf16x8& lo) {
    float f[8] = {a.x, a.y, a.z, a.w, b.x, b.y, b.z, b.w};
#pragma unroll
    for (int j = 0; j < 8; j++) {
        unsigned u = __float_as_uint(f[j]);
        hi[j] = (short)(u >> 16);
        float fl = f[j] - __uint_as_float(u & 0xffff0000u);
        lo[j] = (short)(__float_as_uint(fl) >> 16);
    }
}

// ---------------- grid barrier (all blocks co-resident by construction) ----------------
// bars[0] = root, bars[8+g] = group arrival (16 groups of 64 blocks), bars[32+g] = release.
// Monotonic counters, no reset; memset'd before launch.

__device__ inline void gsync(int* bars, int phase) {
    __syncthreads();
    if (threadIdx.x == 0) {
        __threadfence();                      // release: publish this block's writes
        int g = blockIdx.x >> 6;              // 1024/16 = 64 blocks per group
        int a = atomicAdd(&bars[8 + g], 1);
        if (a == phase * 64 - 1) {            // last arrival in group
            atomicAdd(&bars[0], 1);
            while (atomicAdd(&bars[0], 0) < phase * 16)
                __builtin_amdgcn_s_sleep(16);
            atomicAdd(&bars[32 + g], 1);      // release the group
        } else {
            while (atomicAdd(&bars[32 + g], 0) < phase)
                __builtin_amdgcn_s_sleep(16);
        }
        __threadfence();                      // acquire: invalidate stale cache
    }
    __syncthreads();
}

// ---------------- phase bodies ----------------

// prep_w task: one task per (layer, tile) = 112 tasks, body needs 256 threads.
__device__ inline void prep_w_task(const float* __restrict__ Wl, const float* __restrict__ Wr,
                                   short* __restrict__ Whi, short* __restrict__ Wlo,
                                   float (*Wt)[17], int task) {
    int l = task >> 4;
    int tile = task & 15;
    int c0 = tile * 16;
    const float* Wsrc = (c0 < 128) ? Wl + (size_t)l * 16384 : Wr + (size_t)l * 16384;
    int cbase = (c0 < 128) ? c0 : c0 - 128;
    int t = threadIdx.x;
#pragma unroll
    for (int it = 0; it < 8; it++) {
        int idx = it * 256 + t;
        int k = idx >> 4, c = idx & 15;
        Wt[k][c] = Wsrc[(size_t)k * 128 + cbase + c];
    }
    __syncthreads();
    int kt = t >> 6, lane = t & 63, q = (lane >> 4), cl = lane & 15;
    bf16x8 hi, lo;
#pragma unroll
    for (int j = 0; j < 8; j++) {
        short h, lw;
        split1(Wt[kt * 32 + q * 8 + j][cl], h, lw);
        hi[j] = h; lo[j] = lw;
    }
    size_t off = ((((size_t)l * 16 + tile) * 4 + kt) * 64 + lane) * 8;
    *(bf16x8*)(Whi + off) = hi;
    *(bf16x8*)(Wlo + off) = lo;
}

// GEMM phase: blocks 0..511 = col-half 0 (tiles 0..7), 512..1023 = half 1 (tiles 8..15).
// Wave w owns 2 col-tiles; B frags are loop-invariant registers. A arrives pre-split.
__device__ inline void gemm_phase(const short* __restrict__ xhi, const short* __restrict__ xlo,
                                  const short* __restrict__ WhiL, const short* __restrict__ WloL,
                                  const float* __restrict__ blv, const float* __restrict__ brv,
                                  float* __restrict__ xl, float* __restrict__ xr,
                                  int N, int ntiles) {
    int t = threadIdx.x;
    int w = t >> 6, lane = t & 63, q = lane >> 4, cl = lane & 15;
    int half = blockIdx.x >> 9;

    bf16x8 Bh[2][4], Bl[2][4];
    float biasv[2];
    float* op[2];
    int colc[2];
#pragma unroll
    for (int nt = 0; nt < 2; nt++) {
        int tile = half * 8 + w * 2 + nt;
        int col = tile * 16 + cl;
        if (col < 128) { biasv[nt] = blv[col]; op[nt] = xl; colc[nt] = col; }
        else           { biasv[nt] = brv[col - 128]; op[nt] = xr; colc[nt] = col - 128; }
#pragma unroll
        for (int kt = 0; kt < 4; kt++) {
            size_t o = (((size_t)tile * 4 + kt) * 64 + lane) * 8;
            Bh[nt][kt] = *(const bf16x8*)(WhiL + o);
            Bl[nt][kt] = *(const bf16x8*)(WloL + o);
        }
    }

    for (int rt = (blockIdx.x & 511); rt < ntiles; rt += 512) {
        int row = rt * 16 + cl;
        if (row >= N) row = N - 1;
        const short* ph = xhi + (size_t)row * 128 + q * 8;
        const short* pl = xlo + (size_t)row * 128 + q * 8;
        bf16x8 AH[4], AL[4];
#pragma unroll
        for (int kt = 0; kt < 4; kt++) {
            AH[kt] = *(const bf16x8*)(ph + kt * 32);
            AL[kt] = *(const bf16x8*)(pl + kt * 32);
        }

        f32x4 acc0 = {0.f, 0.f, 0.f, 0.f}, acc1 = {0.f, 0.f, 0.f, 0.f};
#pragma unroll
        for (int kt = 0; kt < 4; kt++) {
            acc0 = __builtin_amdgcn_mfma_f32_16x16x32_bf16(AH[kt], Bh[0][kt], acc0, 0, 0, 0);
            acc1 = __builtin_amdgcn_mfma_f32_16x16x32_bf16(AH[kt], Bh[1][kt], acc1, 0, 0, 0);
            acc0 = __builtin_amdgcn_mfma_f32_16x16x32_bf16(AL[kt], Bh[0][kt], acc0, 0, 0, 0);
            acc1 = __builtin_amdgcn_mfma_f32_16x16x32_bf16(AL[kt], Bh[1][kt], acc1, 0, 0, 0);
            acc0 = __builtin_amdgcn_mfma_f32_16x16x32_bf16(AH[kt], Bl[0][kt], acc0, 0, 0, 0);
            acc1 = __builtin_amdgcn_mfma_f32_16x16x32_bf16(AH[kt], Bl[1][kt], acc1, 0, 0, 0);
        }

        // C/D layout: col = lane&15, row = quad*4 + reg  [m89-verified]
#pragma unroll
        for (int nt = 0; nt < 2; nt++) {
            f32x4 a = nt ? acc1 : acc0;
#pragma unroll
            for (int r = 0; r < 4; r++) {
                int orow = rt * 16 + q * 4 + r;
                if (orow < N) op[nt][(size_t)orow * 128 + colc[nt]] = a[r] + biasv[nt];
            }
        }
    }
}

// AGG phase: one node per wave-slot (4096 slots), grid-stride. Same inner loop as before.
__device__ inline void agg_phase(const float4* __restrict__ xl4, const float4* __restrict__ xr4,
                                 const int* __restrict__ off, const int* __restrict__ esrc,
                                 const float4* __restrict__ att4, const float4* __restrict__ bias4,
                                 float4* __restrict__ out4, short* __restrict__ nhi,
                                 short* __restrict__ nlo, int N) {
    int lane = threadIdx.x & 63;
    int sub = lane >> 4;
    int cl = lane & 15;
    float4 atA = att4[2 * cl];
    float4 atB = att4[2 * cl + 1];
    float4 bA = bias4[2 * cl], bB = bias4[2 * cl + 1];

    for (int i = blockIdx.x * 4 + (threadIdx.x >> 6); i < N; i += NBLK * 4) {
        float4 xrA = xr4[(size_t)i * 32 + 2 * cl];
        float4 xrB = xr4[(size_t)i * 32 + 2 * cl + 1];
        int start = off[i];
        int total = off[i + 1] - start + 1;   // + self-loop at slot 0
        int groups = (total + 3) >> 2;

        int k0 = sub;
        int s0 = (k0 < total) ? ((k0 == 0) ? i : esrc[start + k0 - 1]) : i;
        int k1 = 4 + sub;
        int s1 = (k1 < total) ? esrc[start + k1 - 1] : i;
        float4 v0A = xl4[(size_t)s0 * 32 + 2 * cl];
        float4 v0B = xl4[(size_t)s0 * 32 + 2 * cl + 1];
        int k2 = 8 + sub;
        int s2 = (k2 < total) ? esrc[start + k2 - 1] : i;
        float4 v1A = xl4[(size_t)s1 * 32 + 2 * cl];
        float4 v1B = xl4[(size_t)s1 * 32 + 2 * cl + 1];

        float s = 0.f;
        float4 aA = make_float4(0.f, 0.f, 0.f, 0.f);
        float4 aB = make_float4(0.f, 0.f, 0.f, 0.f);

        for (int g = 0; g < groups; g++) {
            int k3 = 4 * (g + 3) + sub;
            int s3 = (k3 < total) ? esrc[start + k3 - 1] : i;
            float4 v2A = xl4[(size_t)s2 * 32 + 2 * cl];
            float4 v2B = xl4[(size_t)s2 * 32 + 2 * cl + 1];

            int kc = 4 * g + sub;
            int valid = kc < total;
            float z0 = v0A.x + xrA.x, z1 = v0A.y + xrA.y, z2 = v0A.z + xrA.z, z3 = v0A.w + xrA.w;
            float z4 = v0B.x + xrB.x, z5 = v0B.y + xrB.y, z6 = v0B.z + xrB.z, z7 = v0B.w + xrB.w;
            z0 = (z0 > 0.f) ? z0 : 0.2f * z0;
            z1 = (z1 > 0.f) ? z1 : 0.2f * z1;
            z2 = (z2 > 0.f) ? z2 : 0.2f * z2;
            z3 = (z3 > 0.f) ? z3 : 0.2f * z3;
            z4 = (z4 > 0.f) ? z4 : 0.2f * z4;
            z5 = (z5 > 0.f) ? z5 : 0.2f * z5;
            z6 = (z6 > 0.f) ? z6 : 0.2f * z6;
            z7 = (z7 > 0.f) ? z7 : 0.2f * z7;
            float p = z0 * atA.x + z1 * atA.y + z2 * atA.z + z3 * atA.w
                    + z4 * atB.x + z5 * atB.y + z6 * atB.z + z7 * atB.w;
            p += __shfl_xor(p, 1, 64);
            p = fminf(fmaxf(p, -80.f), 80.f);
            float wgt = valid ? __expf(p) : 0.f;
            s += wgt;
            aA.x += wgt * v0A.x; aA.y += wgt * v0A.y; aA.z += wgt * v0A.z; aA.w += wgt * v0A.w;
            aB.x += wgt * v0B.x; aB.y += wgt * v0B.y; aB.z += wgt * v0B.z; aB.w += wgt * v0B.w;

            v0A = v1A; v0B = v1B;
            v1A = v2A; v1B = v2B;
            s2 = s3;
        }

#pragma unroll
        for (int o = 16; o <= 32; o <<= 1) {
            s += __shfl_xor(s, o, 64);
            aA.x += __shfl_xor(aA.x, o, 64); aA.y += __shfl_xor(aA.y, o, 64);
            aA.z += __shfl_xor(aA.z, o, 64); aA.w += __shfl_xor(aA.w, o, 64);
            aB.x += __shfl_xor(aB.x, o, 64); aB.y += __shfl_xor(aB.y, o, 64);
            aB.z += __shfl_xor(aB.z, o, 64); aB.w += __shfl_xor(aB.w, o, 64);
        }
        if (sub == 0) {
            float inv = 1.f / (s + 1e-16f);
            float4 oA, oB;
            oA.x = aA.x * inv + bA.x; oA.y = aA.y * inv + bA.y;
            oA.z = aA.z * inv + bA.z; oA.w = aA.w * inv + bA.w;
            oB.x = aB.x * inv + bB.x; oB.y = aB.y * inv + bB.y;
            oB.z = aB.z * inv + bB.z; oB.w = aB.w * inv + bB.w;
            out4[(size_t)i * 32 + 2 * cl] = oA;
            out4[(size_t)i * 32 + 2 * cl + 1] = oB;
            if (nhi) {
                bf16x8 h, lw;
                cvt8(oA, oB, h, lw);
                *(bf16x8*)(nhi + (size_t)i * 128 + cl * 8) = h;
                *(bf16x8*)(nlo + (size_t)i * 128 + cl * 8) = lw;
            }
        }
    }
}

// head: one output element per wave, grid-stride.
__device__ inline void head_phase(const float* __restrict__ x, const float* __restrict__ wv,
                                  const float* __restrict__ bh, const int* __restrict__ nch,
                                  float* __restrict__ out, int n_out, int N) {
    int lane = threadIdx.x & 63;
    int chunk = 2 + nch[0];
    float w0 = wv[lane], w1 = wv[64 + lane];
    for (int b = blockIdx.x * 4 + (threadIdx.x >> 6); b < n_out; b += NBLK * 4) {
        int row = (b >> 1) * chunk + (b & 1);
        if (row >= N) continue;
        float p = x[(size_t)row * 128 + lane] * w0 + x[(size_t)row * 128 + 64 + lane] * w1;
#pragma unroll
        for (int o = 1; o <= 32; o <<= 1) p += __shfl_xor(p, o, 64);
        if (lane == 0) out[b] = p + bh[0];
    }
}

// ---------------- mega kernel: whole pipeline, 17 grid barriers ----------------

__global__ __launch_bounds__(TPB, 4) void mega(
    const float* __restrict__ x0, const int* __restrict__ ei, const int* __restrict__ nch,
    const float* __restrict__ Wl, const float* __restrict__ Wr,
    const float* __restrict__ blv, const float* __restrict__ brv,
    const float* __restrict__ att, const float* __restrict__ bias,
    const float* __restrict__ wh, const float* __restrict__ bh,
    float* xl, float* xr, float* xA, float* xB,
    short* cvH0, short* cvL0, short* cvH1, short* cvL1,
    short* Whi, short* Wlo,
    int* bars, int* deg, int* off, int* cur, int* esrc,
    float* out, int N, int E, int ntiles, int n_out) {

    __shared__ float Wt[128][17];
    int t = threadIdx.x;
    int b = blockIdx.x;

    // ---- P0: prep_w (112 tasks) + cvt_x + degree count ----
    if (b < 112) prep_w_task(Wl, Wr, Whi, Wlo, Wt, b);
    {
        int n8 = N * 16;
        for (int id = b * TPB + t; id < n8; id += NBLK * TPB) {
            const float4* x4 = (const float4*)x0;
            float4 a = x4[2 * id];
            float4 bb = x4[2 * id + 1];
            bf16x8 h, lw;
            cvt8(a, bb, h, lw);
            *(bf16x8*)(cvH0 + (size_t)id * 8) = h;
            *(bf16x8*)(cvL0 + (size_t)id * 8) = lw;
        }
    }
    {
        int is64 = detect_is64(ei);
        for (int e = b * TPB + t; e < E; e += NBLK * TPB) {
            long long pos = (long long)E + e;
            int d = ei[is64 ? 2 * pos : pos];
            if ((unsigned)d < (unsigned)N) atomicAdd(&deg[d], 1);
        }
    }
    gsync(bars, 1);

    // ---- P1: scan (block 0 only) ----
    if (b == 0) {
        __shared__ int wsum[4];
        int per = (N + 255) >> 8;
        int b0 = t * per;
        int s = 0;
        for (int k = 0; k < per; k++) {
            int idx = b0 + k;
            if (idx < N) s += deg[idx];
        }
        int lane = t & 63, w = t >> 6;
        int v = s;
#pragma unroll
        for (int o = 1; o < 64; o <<= 1) {
            int u = __shfl_up(v, o, 64);
            if (lane >= o) v += u;
        }
        if (lane == 63) wsum[w] = v;
        __syncthreads();
        if (t == 0) {
            int r = 0;
#pragma unroll
            for (int j = 0; j < 4; j++) { int xx = wsum[j]; wsum[j] = r; r += xx; }
            off[N] = r;
        }
        __syncthreads();
        int run = v - s + wsum[w];
        for (int k = 0; k < per; k++) {
            int idx = b0 + k;
            if (idx < N) {
                off[idx] = run;
                cur[idx] = run;
                run += deg[idx];
            }
        }
    }
    gsync(bars, 2);

    // ---- P2: fill ----
    {
        int is64 = detect_is64(ei);
        for (int e = b * TPB + t; e < E; e += NBLK * TPB) {
            long long spos = e, dpos = (long long)E + e;
            int s = ei[is64 ? 2 * spos : spos];
            int d = ei[is64 ? 2 * dpos : dpos];
            if ((unsigned)d >= (unsigned)N || (unsigned)s >= (unsigned)N) continue;
            int p = atomicAdd(&cur[d], 1);
            esrc[p] = s;
        }
    }
    gsync(bars, 3);

    // ---- layers ----
    short* inH = cvH0; short* inL = cvL0;
    short* otH = cvH1; short* otL = cvL1;
    float* xn = xA;
    float* xfin = xB;
    int phase = 4;
    for (int l = 0; l < 7; l++) {
        gemm_phase(inH, inL, Whi + (size_t)l * WFRAG, Wlo + (size_t)l * WFRAG,
                   blv + (size_t)l * 128, brv + (size_t)l * 128, xl, xr, N, ntiles);
        gsync(bars, phase++);
        int last = (l == 6);
        agg_phase((const float4*)xl, (const float4*)xr, off, esrc,
                  (const float4*)(att + (size_t)l * 128),
                  (const float4*)(bias + (size_t)l * 128),
                  (float4*)xn, last ? (short*)0 : otH, last ? (short*)0 : otL, N);
        gsync(bars, phase++);
        xfin = xn;
        xn = (xn == xA) ? xB : xA;
        short* th = inH; short* tl = inL;
        inH = otH; inL = otL;
        otH = th; otL = tl;
    }

    // ---- head ----
    head_phase(xfin, wh, bh, nch, out, n_out, N);
}

// ---------------- launch ----------------

extern "C" void kernel_launch(void* const* d_in, const int* in_sizes, int n_in,
                              void* d_out, int out_size, void* d_ws, size_t ws_size,
                              hipStream_t stream) {
    const float* x0 = (const float*)d_in[0];
    const int* ei = (const int*)d_in[1];
    const int* nchunks = (const int*)d_in[2];
    const float* Wl = (const float*)d_in[3];
    const float* bl = (const float*)d_in[4];
    const float* Wr = (const float*)d_in[5];
    const float* br = (const float*)d_in[6];
    const float* att = (const float*)d_in[7];
    const float* bias = (const float*)d_in[8];
    const float* wh = (const float*)d_in[9];
    const float* bh = (const float*)d_in[10];

    const int D = 128;
    int N = in_sizes[0] / D;   // 10000
    int E = in_sizes[1] / 2;   // 160000
    int ntiles = (N + 15) / 16;

    size_t fN = (size_t)N * D;
    float* xl = (float*)d_ws;
    float* xr = xl + fN;
    float* xA = xr + fN;
    float* xB = xA + fN;
    short* cvH0 = (short*)(xB + fN);
    short* cvL0 = cvH0 + fN;
    short* cvH1 = cvL0 + fN;
    short* cvL1 = cvH1 + fN;
    short* Whi = cvL1 + fN;
    short* Wlo = Whi + 7 * (size_t)WFRAG;
    int* bars = (int*)(Wlo + 7 * (size_t)WFRAG);
    int* deg = bars + 64;
    int* off = deg + N;
    int* cur = off + N + 1;
    int* esrc = cur + N;

    // zero barrier counters + degree array in one memset
    hipMemsetAsync(bars, 0, (64 + (size_t)N) * sizeof(int), stream);

    mega<<<NBLK, TPB, 0, stream>>>(x0, ei, nchunks, Wl, Wr, bl, br, att, bias, wh, bh,
                                   xl, xr, xA, xB, cvH0, cvL0, cvH1, cvL1, Whi, Wlo,
                                   bars, deg, off, cur, esrc,
                                   (float*)d_out, N, E, ntiles, out_size);
}

// Round 6
// 272.844 us; speedup vs baseline: 4.5041x; 4.5041x over previous
//
#include <hip/hip_runtime.h>
#include <math.h>

typedef __attribute__((ext_vector_type(8))) short bf16x8;
typedef __attribute__((ext_vector_type(4))) float f32x4;

#define WFRAG (16 * 4 * 64 * 8)

// ---------------- helpers ----------------

__device__ inline int detect_is64(const int* __restrict__ ei) {
    int is64 = 1;
#pragma unroll
    for (int k = 1; k < 16; k += 2) is64 &= (ei[k] == 0);
    return is64;
}

__device__ inline void split1(float f, short& hi, short& lo) {
    unsigned u = __float_as_uint(f);
    hi = (short)(u >> 16);
    float fl = f - __uint_as_float(u & 0xffff0000u);
    lo = (short)(__float_as_uint(fl) >> 16);
}

__device__ inline void cvt8(const float4& a, const float4& b, bf16x8& hi, bf16x8& lo) {
    float f[8] = {a.x, a.y, a.z, a.w, b.x, b.y, b.z, b.w};
#pragma unroll
    for (int j = 0; j < 8; j++) {
        unsigned u = __float_as_uint(f[j]);
        hi[j] = (short)(u >> 16);
        float fl = f[j] - __uint_as_float(u & 0xffff0000u);
        lo[j] = (short)(__float_as_uint(fl) >> 16);
    }
}

// ---------------- prologue: prep_w (blocks 0..111) + cvt_x + degree count ----------------

__global__ __launch_bounds__(256) void prologue(const float* __restrict__ Wl,
                                                const float* __restrict__ Wr,
                                                short* __restrict__ Whi,
                                                short* __restrict__ Wlo,
                                                const float4* __restrict__ x4,
                                                short* __restrict__ cvH,
                                                short* __restrict__ cvL,
                                                const int* __restrict__ ei,
                                                int* __restrict__ deg,
                                                int N, int E) {
    __shared__ float Wt[128][17];
    int b = blockIdx.x, t = threadIdx.x;
    if (b < 112) {
        // prep_w task: layer l = b>>4, tile = b&15
        int l = b >> 4;
        int tile = b & 15;
        int c0 = tile * 16;
        const float* Wsrc = (c0 < 128) ? Wl + (size_t)l * 16384 : Wr + (size_t)l * 16384;
        int cbase = (c0 < 128) ? c0 : c0 - 128;
#pragma unroll
        for (int it = 0; it < 8; it++) {
            int idx = it * 256 + t;
            int k = idx >> 4, c = idx & 15;
            Wt[k][c] = Wsrc[(size_t)k * 128 + cbase + c];
        }
        __syncthreads();
        int kt = t >> 6, lane = t & 63, q = (lane >> 4), cl = lane & 15;
        bf16x8 hi, lo;
#pragma unroll
        for (int j = 0; j < 8; j++) {
            short h, lw;
            split1(Wt[kt * 32 + q * 8 + j][cl], h, lw);
            hi[j] = h; lo[j] = lw;
        }
        size_t off = ((((size_t)l * 16 + tile) * 4 + kt) * 64 + lane) * 8;
        *(bf16x8*)(Whi + off) = hi;
        *(bf16x8*)(Wlo + off) = lo;
        return;
    }
    int rb = b - 112;
    int RB = gridDim.x - 112;
    // cvt_x: split x0 into hi/lo bf16
    int n8 = N * 16;
    for (int id = rb * 256 + t; id < n8; id += RB * 256) {
        float4 a = x4[2 * id];
        float4 bb = x4[2 * id + 1];
        bf16x8 h, lw;
        cvt8(a, bb, h, lw);
        *(bf16x8*)(cvH + (size_t)id * 8) = h;
        *(bf16x8*)(cvL + (size_t)id * 8) = lw;
    }
    // degree count
    int is64 = detect_is64(ei);
    for (int e = rb * 256 + t; e < E; e += RB * 256) {
        long long pos = (long long)E + e;
        int d = ei[is64 ? 2 * pos : pos];
        if ((unsigned)d < (unsigned)N) atomicAdd(&deg[d], 1);
    }
}

// ---------------- CSR scan + fill ----------------

__global__ __launch_bounds__(1024) void scan_kernel(const int* __restrict__ deg,
                                                    int* __restrict__ off,
                                                    int* __restrict__ cur, int N) {
    __shared__ int wsum[16];
    int t = threadIdx.x;
    int per = (N + 1023) >> 10;
    int b0 = t * per;
    int s = 0;
    for (int k = 0; k < per; k++) {
        int idx = b0 + k;
        if (idx < N) s += deg[idx];
    }
    int lane = t & 63, w = t >> 6;
    int v = s;
#pragma unroll
    for (int o = 1; o < 64; o <<= 1) {
        int u = __shfl_up(v, o, 64);
        if (lane >= o) v += u;
    }
    if (lane == 63) wsum[w] = v;
    __syncthreads();
    if (t == 0) {
        int r = 0;
#pragma unroll
        for (int j = 0; j < 16; j++) { int xx = wsum[j]; wsum[j] = r; r += xx; }
        off[N] = r;
    }
    __syncthreads();
    int run = v - s + wsum[w];
    for (int k = 0; k < per; k++) {
        int idx = b0 + k;
        if (idx < N) {
            off[idx] = run;
            cur[idx] = run;
            run += deg[idx];
        }
    }
}

__global__ void fill_kernel(const int* __restrict__ ei, int E, int N,
                            int* __restrict__ cur, int* __restrict__ esrc) {
    int e = blockIdx.x * blockDim.x + threadIdx.x;
    if (e >= E) return;
    int is64 = detect_is64(ei);
    long long spos = e, dpos = (long long)E + e;
    int s = ei[is64 ? 2 * spos : spos];
    int d = ei[is64 ? 2 * dpos : dpos];
    if ((unsigned)d >= (unsigned)N || (unsigned)s >= (unsigned)N) return;
    int p = atomicAdd(&cur[d], 1);
    esrc[p] = s;
}

// ---------------- standalone GEMM (layer 0): A pre-split from prologue ----------------

__global__ __launch_bounds__(512, 1) void gemm_xlxr(const short* __restrict__ xhi,
                                                    const short* __restrict__ xlo,
                                                    const short* __restrict__ WhiL,
                                                    const short* __restrict__ WloL,
                                                    const float* __restrict__ blv,
                                                    const float* __restrict__ brv,
                                                    float* __restrict__ xl,
                                                    float* __restrict__ xr,
                                                    int N, int ntiles) {
    int t = threadIdx.x;
    int w = t >> 6, lane = t & 63, q = lane >> 4, cl = lane & 15;

    bf16x8 Bh[2][4], Bl[2][4];
    float biasv[2];
    float* op[2];
    int colc[2];
#pragma unroll
    for (int nt = 0; nt < 2; nt++) {
        int tile = w * 2 + nt;
        int col = tile * 16 + cl;
        if (col < 128) { biasv[nt] = blv[col]; op[nt] = xl; colc[nt] = col; }
        else           { biasv[nt] = brv[col - 128]; op[nt] = xr; colc[nt] = col - 128; }
#pragma unroll
        for (int kt = 0; kt < 4; kt++) {
            size_t o = (((size_t)tile * 4 + kt) * 64 + lane) * 8;
            Bh[nt][kt] = *(const bf16x8*)(WhiL + o);
            Bl[nt][kt] = *(const bf16x8*)(WloL + o);
        }
    }

    for (int rt = blockIdx.x; rt < ntiles; rt += gridDim.x) {
        int row = rt * 16 + cl;
        if (row >= N) row = N - 1;
        const short* ph = xhi + (size_t)row * 128 + q * 8;
        const short* pl = xlo + (size_t)row * 128 + q * 8;
        bf16x8 AH[4], AL[4];
#pragma unroll
        for (int kt = 0; kt < 4; kt++) {
            AH[kt] = *(const bf16x8*)(ph + kt * 32);
            AL[kt] = *(const bf16x8*)(pl + kt * 32);
        }

        f32x4 acc0 = {0.f, 0.f, 0.f, 0.f}, acc1 = {0.f, 0.f, 0.f, 0.f};
#pragma unroll
        for (int kt = 0; kt < 4; kt++) {
            acc0 = __builtin_amdgcn_mfma_f32_16x16x32_bf16(AH[kt], Bh[0][kt], acc0, 0, 0, 0);
            acc1 = __builtin_amdgcn_mfma_f32_16x16x32_bf16(AH[kt], Bh[1][kt], acc1, 0, 0, 0);
            acc0 = __builtin_amdgcn_mfma_f32_16x16x32_bf16(AL[kt], Bh[0][kt], acc0, 0, 0, 0);
            acc1 = __builtin_amdgcn_mfma_f32_16x16x32_bf16(AL[kt], Bh[1][kt], acc1, 0, 0, 0);
            acc0 = __builtin_amdgcn_mfma_f32_16x16x32_bf16(AH[kt], Bl[0][kt], acc0, 0, 0, 0);
            acc1 = __builtin_amdgcn_mfma_f32_16x16x32_bf16(AH[kt], Bl[1][kt], acc1, 0, 0, 0);
        }

        // C/D layout: col = lane&15, row = quad*4 + reg  [m89-verified]
#pragma unroll
        for (int nt = 0; nt < 2; nt++) {
            f32x4 a = nt ? acc1 : acc0;
#pragma unroll
            for (int r = 0; r < 4; r++) {
                int orow = rt * 16 + q * 4 + r;
                if (orow < N) op[nt][(size_t)orow * 128 + colc[nt]] = a[r] + biasv[nt];
            }
        }
    }
}

// ---------------- agg core: one node per wave (round-2-verified body) ----------------

__device__ inline void agg_node(int i, int sub, int cl,
                                const float4* __restrict__ xl4, const float4* __restrict__ xr4,
                                const int* __restrict__ off, const int* __restrict__ esrc,
                                float4 atA, float4 atB, float4 bA, float4 bB,
                                float4& oA, float4& oB) {
    float4 xrA = xr4[(size_t)i * 32 + 2 * cl];
    float4 xrB = xr4[(size_t)i * 32 + 2 * cl + 1];
    int start = off[i];
    int total = off[i + 1] - start + 1;   // + self-loop at slot 0
    int groups = (total + 3) >> 2;

    int k0 = sub;
    int s0 = (k0 < total) ? ((k0 == 0) ? i : esrc[start + k0 - 1]) : i;
    int k1 = 4 + sub;
    int s1 = (k1 < total) ? esrc[start + k1 - 1] : i;
    float4 v0A = xl4[(size_t)s0 * 32 + 2 * cl];
    float4 v0B = xl4[(size_t)s0 * 32 + 2 * cl + 1];
    int k2 = 8 + sub;
    int s2 = (k2 < total) ? esrc[start + k2 - 1] : i;
    float4 v1A = xl4[(size_t)s1 * 32 + 2 * cl];
    float4 v1B = xl4[(size_t)s1 * 32 + 2 * cl + 1];

    float s = 0.f;
    float4 aA = make_float4(0.f, 0.f, 0.f, 0.f);
    float4 aB = make_float4(0.f, 0.f, 0.f, 0.f);

    for (int g = 0; g < groups; g++) {
        int k3 = 4 * (g + 3) + sub;
        int s3 = (k3 < total) ? esrc[start + k3 - 1] : i;
        float4 v2A = xl4[(size_t)s2 * 32 + 2 * cl];
        float4 v2B = xl4[(size_t)s2 * 32 + 2 * cl + 1];

        int kc = 4 * g + sub;
        int valid = kc < total;
        float z0 = v0A.x + xrA.x, z1 = v0A.y + xrA.y, z2 = v0A.z + xrA.z, z3 = v0A.w + xrA.w;
        float z4 = v0B.x + xrB.x, z5 = v0B.y + xrB.y, z6 = v0B.z + xrB.z, z7 = v0B.w + xrB.w;
        z0 = (z0 > 0.f) ? z0 : 0.2f * z0;
        z1 = (z1 > 0.f) ? z1 : 0.2f * z1;
        z2 = (z2 > 0.f) ? z2 : 0.2f * z2;
        z3 = (z3 > 0.f) ? z3 : 0.2f * z3;
        z4 = (z4 > 0.f) ? z4 : 0.2f * z4;
        z5 = (z5 > 0.f) ? z5 : 0.2f * z5;
        z6 = (z6 > 0.f) ? z6 : 0.2f * z6;
        z7 = (z7 > 0.f) ? z7 : 0.2f * z7;
        float p = z0 * atA.x + z1 * atA.y + z2 * atA.z + z3 * atA.w
                + z4 * atB.x + z5 * atB.y + z6 * atB.z + z7 * atB.w;
        p += __shfl_xor(p, 1, 64);
        p = fminf(fmaxf(p, -80.f), 80.f);
        float wgt = valid ? __expf(p) : 0.f;
        s += wgt;
        aA.x += wgt * v0A.x; aA.y += wgt * v0A.y; aA.z += wgt * v0A.z; aA.w += wgt * v0A.w;
        aB.x += wgt * v0B.x; aB.y += wgt * v0B.y; aB.z += wgt * v0B.z; aB.w += wgt * v0B.w;

        v0A = v1A; v0B = v1B;
        v1A = v2A; v1B = v2B;
        s2 = s3;
    }

#pragma unroll
    for (int o = 16; o <= 32; o <<= 1) {
        s += __shfl_xor(s, o, 64);
        aA.x += __shfl_xor(aA.x, o, 64); aA.y += __shfl_xor(aA.y, o, 64);
        aA.z += __shfl_xor(aA.z, o, 64); aA.w += __shfl_xor(aA.w, o, 64);
        aB.x += __shfl_xor(aB.x, o, 64); aB.y += __shfl_xor(aB.y, o, 64);
        aB.z += __shfl_xor(aB.z, o, 64); aB.w += __shfl_xor(aB.w, o, 64);
    }
    float inv = 1.f / (s + 1e-16f);
    oA.x = aA.x * inv + bA.x; oA.y = aA.y * inv + bA.y;
    oA.z = aA.z * inv + bA.z; oA.w = aA.w * inv + bA.w;
    oB.x = aB.x * inv + bB.x; oB.y = aB.y * inv + bB.y;
    oB.z = aB.z * inv + bB.z; oB.w = aB.w * inv + bB.w;
}

// ---------------- fused agg(l) + gemm(l+1): one block = one 16-row tile ----------------
// 4 waves x 4 sequential nodes -> split-bf16 rows in LDS -> 16x256 MFMA tile.
// Cross-block gather reads only previous-kernel data (xl/xr double-buffered) -> no fences.

__global__ __launch_bounds__(256) void agg_gemm(const float4* __restrict__ xl4,
                                                const float4* __restrict__ xr4,
                                                const int* __restrict__ off,
                                                const int* __restrict__ esrc,
                                                const float4* __restrict__ att4,
                                                const float4* __restrict__ bias4,
                                                const short* __restrict__ WhiL,
                                                const short* __restrict__ WloL,
                                                const float* __restrict__ blv,
                                                const float* __restrict__ brv,
                                                float* __restrict__ xlo_out,
                                                float* __restrict__ xro_out,
                                                int N) {
    __shared__ __align__(16) short hiL[16 * 136];
    __shared__ __align__(16) short loL[16 * 136];
    int t = threadIdx.x;
    int w = t >> 6, lane = t & 63, sub = lane >> 4, cl = lane & 15, q = lane >> 4;
    int base = blockIdx.x * 16;

    float4 atA = att4[2 * cl];
    float4 atB = att4[2 * cl + 1];
    float4 bA = bias4[2 * cl], bB = bias4[2 * cl + 1];

    // ---- agg: 4 nodes per wave ----
    for (int j = 0; j < 4; j++) {
        int i = base + w * 4 + j;
        if (i < N) {
            float4 oA, oB;
            agg_node(i, sub, cl, xl4, xr4, off, esrc, atA, atB, bA, bB, oA, oB);
            if (sub == 0) {
                bf16x8 h, lw;
                cvt8(oA, oB, h, lw);
                int r = w * 4 + j;
                *(bf16x8*)&hiL[r * 136 + cl * 8] = h;
                *(bf16x8*)&loL[r * 136 + cl * 8] = lw;
            }
        }
    }
    __syncthreads();

    // ---- gemm: A frags from LDS (row = cl, elems kt*32 + q*8 + j) ----
    bf16x8 Ah[4], Al[4];
#pragma unroll
    for (int kt = 0; kt < 4; kt++) {
        Ah[kt] = *(const bf16x8*)&hiL[cl * 136 + kt * 32 + q * 8];
        Al[kt] = *(const bf16x8*)&loL[cl * 136 + kt * 32 + q * 8];
    }

#pragma unroll
    for (int tt = 0; tt < 4; tt++) {
        int tile = w * 4 + tt;
        int col = tile * 16 + cl;
        f32x4 acc = {0.f, 0.f, 0.f, 0.f};
#pragma unroll
        for (int kt = 0; kt < 4; kt++) {
            size_t o = (((size_t)tile * 4 + kt) * 64 + lane) * 8;
            bf16x8 bh = *(const bf16x8*)(WhiL + o);
            bf16x8 bl2 = *(const bf16x8*)(WloL + o);
            acc = __builtin_amdgcn_mfma_f32_16x16x32_bf16(Ah[kt], bh, acc, 0, 0, 0);
            acc = __builtin_amdgcn_mfma_f32_16x16x32_bf16(Al[kt], bh, acc, 0, 0, 0);
            acc = __builtin_amdgcn_mfma_f32_16x16x32_bf16(Ah[kt], bl2, acc, 0, 0, 0);
        }
        float biasv;
        float* op;
        int cc;
        if (col < 128) { biasv = blv[col]; op = xlo_out; cc = col; }
        else           { biasv = brv[col - 128]; op = xro_out; cc = col - 128; }
#pragma unroll
        for (int r = 0; r < 4; r++) {
            int row = base + q * 4 + r;
            if (row < N) op[(size_t)row * 128 + cc] = acc[r] + biasv;
        }
    }
}

// ---------------- standalone agg (layer 6) ----------------

__global__ __launch_bounds__(256) void gat_agg(const float4* __restrict__ xl4,
                                               const float4* __restrict__ xr4,
                                               const int* __restrict__ off,
                                               const int* __restrict__ esrc,
                                               const float4* __restrict__ att4,
                                               const float4* __restrict__ bias4,
                                               float4* __restrict__ out4, int N) {
    int lane = threadIdx.x & 63;
    int sub = lane >> 4;
    int cl = lane & 15;
    int i = blockIdx.x * 4 + (threadIdx.x >> 6);
    if (i >= N) return;
    float4 atA = att4[2 * cl];
    float4 atB = att4[2 * cl + 1];
    float4 bA = bias4[2 * cl], bB = bias4[2 * cl + 1];
    float4 oA, oB;
    agg_node(i, sub, cl, xl4, xr4, off, esrc, atA, atB, bA, bB, oA, oB);
    if (sub == 0) {
        out4[(size_t)i * 32 + 2 * cl] = oA;
        out4[(size_t)i * 32 + 2 * cl + 1] = oB;
    }
}

// ---------------- head ----------------

__global__ __launch_bounds__(128) void head_kernel(const float* __restrict__ x,
                                                   const float* __restrict__ w,
                                                   const float* __restrict__ bh,
                                                   const int* __restrict__ nch,
                                                   float* __restrict__ out) {
    __shared__ float r[2];
    int b = blockIdx.x, t = threadIdx.x;
    int chunk = 2 + nch[0];
    int row = (b >> 1) * chunk + (b & 1);
    float p = x[(size_t)row * 128 + t] * w[t];
#pragma unroll
    for (int o = 32; o >= 1; o >>= 1) p += __shfl_xor(p, o, 64);
    if ((t & 63) == 0) r[t >> 6] = p;
    __syncthreads();
    if (t == 0) out[b] = r[0] + r[1] + bh[0];
}

// ---------------- launch ----------------

extern "C" void kernel_launch(void* const* d_in, const int* in_sizes, int n_in,
                              void* d_out, int out_size, void* d_ws, size_t ws_size,
                              hipStream_t stream) {
    const float* x0 = (const float*)d_in[0];
    const int* ei = (const int*)d_in[1];
    const int* nchunks = (const int*)d_in[2];
    const float* Wl = (const float*)d_in[3];
    const float* bl = (const float*)d_in[4];
    const float* Wr = (const float*)d_in[5];
    const float* br = (const float*)d_in[6];
    const float* att = (const float*)d_in[7];
    const float* bias = (const float*)d_in[8];
    const float* wh = (const float*)d_in[9];
    const float* bh = (const float*)d_in[10];

    const int D = 128;
    int N = in_sizes[0] / D;   // 10000
    int E = in_sizes[1] / 2;   // 160000
    int ntiles = (N + 15) / 16;

    size_t fN = (size_t)N * D;
    float* xlA = (float*)d_ws;
    float* xrA = xlA + fN;
    float* xlB = xrA + fN;
    float* xrB = xlB + fN;
    float* xout = xrB + fN;
    short* cvH0 = (short*)(xout + fN);
    short* cvL0 = cvH0 + fN;
    short* Whi = cvL0 + fN;
    short* Wlo = Whi + 7 * (size_t)WFRAG;
    int* deg = (int*)(Wlo + 7 * (size_t)WFRAG);
    int* off = deg + N;
    int* cur = off + N + 1;
    int* esrc = cur + N;

    hipMemsetAsync(deg, 0, (size_t)N * sizeof(int), stream);
    prologue<<<112 + 640, 256, 0, stream>>>(Wl, Wr, Whi, Wlo, (const float4*)x0,
                                            cvH0, cvL0, ei, deg, N, E);
    scan_kernel<<<1, 1024, 0, stream>>>(deg, off, cur, N);
    fill_kernel<<<(E + 255) / 256, 256, 0, stream>>>(ei, E, N, cur, esrc);

    // layer-0 projection
    gemm_xlxr<<<256, 512, 0, stream>>>(cvH0, cvL0, Whi, Wlo, bl, br, xlA, xrA, N, ntiles);

    // layers 0..5: fused agg(l) + gemm(l+1), ping-pong xl/xr pairs
    for (int l = 0; l < 6; l++) {
        const float* rxl = (l % 2 == 0) ? xlA : xlB;
        const float* rxr = (l % 2 == 0) ? xrA : xrB;
        float* wxl = (l % 2 == 0) ? xlB : xlA;
        float* wxr = (l % 2 == 0) ? xrB : xrA;
        agg_gemm<<<ntiles, 256, 0, stream>>>((const float4*)rxl, (const float4*)rxr, off, esrc,
                                             (const float4*)(att + (size_t)l * D),
                                             (const float4*)(bias + (size_t)l * D),
                                             Whi + (size_t)(l + 1) * WFRAG,
                                             Wlo + (size_t)(l + 1) * WFRAG,
                                             bl + (size_t)(l + 1) * D,
                                             br + (size_t)(l + 1) * D,
                                             wxl, wxr, N);
    }

    // layer 6: standalone agg -> fp32 node features
    gat_agg<<<(N + 3) / 4, 256, 0, stream>>>((const float4*)xlA, (const float4*)xrA, off, esrc,
                                             (const float4*)(att + 6 * (size_t)D),
                                             (const float4*)(bias + 6 * (size_t)D),
                                             (float4*)xout, N);

    head_kernel<<<out_size, 128, 0, stream>>>(xout, wh, bh, nchunks, (float*)d_out);
}